// Round 1
// baseline (5639.334 us; speedup 1.0000x reference)
//
#include <hip/hip_runtime.h>

#define T_STEPS 8

// ---- sizes (floats) ----
#define N_L1 (32*64*32*32)     // 2,097,152
#define N_M2 (32*128*32*32)    // 4,194,304
#define N_P2 (32*128*16*16)    // 1,048,576
#define N_M3 N_P2
#define N_P3 (32*8192)         // 262,144
#define N_C1 (32*1024)
#define N_C2 (32*10)

// ---- workspace offsets (floats) ----
#define OFF_A1  0
#define OFF_M1  (OFF_A1 + N_L1)
#define OFF_S1  (OFF_M1 + N_L1)
#define OFF_M2  (OFF_S1 + N_L1)
#define OFF_P2  (OFF_M2 + N_M2)
#define OFF_M3  (OFF_P2 + N_P2)
#define OFF_P3  (OFF_M3 + N_M3)
#define OFF_C1  (OFF_P3 + N_P3)
#define OFF_SF1 (OFF_C1 + N_C1)
#define OFF_C2  (OFF_SF1 + N_C1)
#define WS_FLOATS (OFF_C2 + N_C2)

// ---------------- conv1 (runs once; X constant across timesteps) ----------------
__global__ __launch_bounds__(256) void k_conv1(const float* __restrict__ X,
    const float* __restrict__ w, const float* __restrict__ bias,
    float* __restrict__ A1) {
  int idx = blockIdx.x * 256 + threadIdx.x;          // (b,oc,y,x)
  int x = idx & 31, y = (idx >> 5) & 31, oc = (idx >> 10) & 63, b = idx >> 16;
  float acc = bias[oc];
  for (int ic = 0; ic < 3; ++ic) {
    const float* xp = X + (b*3 + ic)*1024;
    const float* wp = w + (oc*3 + ic)*9;
    #pragma unroll
    for (int dy = 0; dy < 3; ++dy) {
      int iy = y + dy - 1;
      if (iy < 0 || iy > 31) continue;
      #pragma unroll
      for (int dx = 0; dx < 3; ++dx) {
        int ix = x + dx - 1;
        if (ix < 0 || ix > 31) continue;
        acc = fmaf(xp[iy*32 + ix], wp[dy*3 + dx], acc);
      }
    }
  }
  A1[idx] = acc;
}

// ---------------- layer-1 LIF + dropout-mask (elementwise) ----------------
__global__ __launch_bounds__(256) void k_lif1(const float* __restrict__ A1,
    const float* __restrict__ mask, float* __restrict__ m1, float* __restrict__ s1) {
  int i = blockIdx.x * 256 + threadIdx.x;
  float m = m1[i] + A1[i];
  float spk = (m >= 1.0f) ? 1.0f : 0.0f;
  m1[i] = m - spk;
  s1[i] = spk * mask[i];
}

// ---------------- conv2 + LIF(m2) + 2x2 mean-pool ----------------
// grid 512: b(32) x ocg(4, 32 oc each) x tile(4, 16x16 spatial quarters)
__global__ __launch_bounds__(256, 2) void k_conv2(const float* __restrict__ s1,
    const float* __restrict__ w, const float* __restrict__ bias,
    float* __restrict__ m2, float* __restrict__ p2) {
  int bid = blockIdx.x;
  int tile = bid & 3;
  int ocg  = (bid >> 2) & 3;
  int b    = bid >> 4;
  int ty0 = (tile >> 1) * 16, tx0 = (tile & 1) * 16;
  int t = threadIdx.x;
  int ty = t >> 4, tx = t & 15;

  __shared__ float lds[32 * 324];   // 32 ic x 18x18 = 41.5 KB
  float acc[32];
  #pragma unroll
  for (int o = 0; o < 32; ++o) acc[o] = 0.f;

  for (int chunk = 0; chunk < 2; ++chunk) {
    const float* src = s1 + (size_t)(b*64 + chunk*32) * 1024;
    __syncthreads();
    for (int i = t; i < 32*324; i += 256) {
      int ic = i / 324;
      int rr = i - ic*324;
      int ry = rr / 18;
      int rx = rr - ry*18;
      int iy = ty0 + ry - 1;
      int ix = tx0 + rx - 1;
      float v = 0.f;
      if (iy >= 0 && iy < 32 && ix >= 0 && ix < 32)
        v = src[ic*1024 + iy*32 + ix];
      lds[i] = v;
    }
    __syncthreads();
    const float* wc = w + (size_t)(ocg*32)*576 + chunk*32*9;
    for (int ic = 0; ic < 32; ++ic) {
      float in9[9];
      #pragma unroll
      for (int dy = 0; dy < 3; ++dy)
        #pragma unroll
        for (int dx = 0; dx < 3; ++dx)
          in9[dy*3+dx] = lds[ic*324 + (ty+dy)*18 + (tx+dx)];
      #pragma unroll
      for (int o = 0; o < 32; ++o) {
        const float* wp = wc + o*576 + ic*9;
        #pragma unroll
        for (int k = 0; k < 9; ++k)
          acc[o] = fmaf(in9[k], wp[k], acc[o]);
      }
    }
  }

  // epilogue: bias + LIF + pool(spikes)
  int y = ty0 + ty, x = tx0 + tx;
  bool writer = ((tx & 1) == 0) && ((ty & 1) == 0);
  int py = y >> 1, px = x >> 1;
  #pragma unroll
  for (int o = 0; o < 32; ++o) {
    int oc = ocg*32 + o;
    size_t mi = (size_t)(b*128 + oc)*1024 + y*32 + x;
    float m = m2[mi] + acc[o] + bias[oc];
    float spk = (m >= 1.0f) ? 1.0f : 0.0f;
    m2[mi] = m - spk;
    float s = spk;
    s += __shfl_xor(s, 1);    // x-neighbor (lane bit0)
    s += __shfl_xor(s, 16);   // y-neighbor (lane bit4: 64 lanes = 4 rows of 16)
    if (writer)
      p2[(size_t)(b*128 + oc)*256 + py*16 + px] = s * 0.25f;
  }
}

// ---------------- conv3 + LIF(m3) + mask_f2 + 2x2 mean-pool ----------------
// grid 512: b(32) x ocg(16, 8 oc each); 256 thr = whole 16x16 plane
__global__ __launch_bounds__(256, 2) void k_conv3(const float* __restrict__ p2,
    const float* __restrict__ w, const float* __restrict__ bias,
    const float* __restrict__ mf2, float* __restrict__ m3, float* __restrict__ p3) {
  int bid = blockIdx.x;
  int ocg = bid & 15;
  int b   = bid >> 4;
  int t = threadIdx.x;
  int ty = t >> 4, tx = t & 15;

  __shared__ float lds[16 * 324];   // 16 ic x 18x18 = 20.7 KB
  float acc[8];
  #pragma unroll
  for (int o = 0; o < 8; ++o) acc[o] = 0.f;

  for (int chunk = 0; chunk < 8; ++chunk) {
    const float* src = p2 + (size_t)(b*128 + chunk*16) * 256;
    __syncthreads();
    for (int i = t; i < 16*324; i += 256) {
      int ic = i / 324;
      int rr = i - ic*324;
      int ry = rr / 18;
      int rx = rr - ry*18;
      int iy = ry - 1;
      int ix = rx - 1;
      float v = 0.f;
      if (iy >= 0 && iy < 16 && ix >= 0 && ix < 16)
        v = src[ic*256 + iy*16 + ix];
      lds[i] = v;
    }
    __syncthreads();
    const float* wc = w + (size_t)(ocg*8)*1152 + chunk*16*9;
    for (int ic = 0; ic < 16; ++ic) {
      float in9[9];
      #pragma unroll
      for (int dy = 0; dy < 3; ++dy)
        #pragma unroll
        for (int dx = 0; dx < 3; ++dx)
          in9[dy*3+dx] = lds[ic*324 + (ty+dy)*18 + (tx+dx)];
      #pragma unroll
      for (int o = 0; o < 8; ++o) {
        const float* wp = wc + o*1152 + ic*9;
        #pragma unroll
        for (int k = 0; k < 9; ++k)
          acc[o] = fmaf(in9[k], wp[k], acc[o]);
      }
    }
  }

  bool writer = ((tx & 1) == 0) && ((ty & 1) == 0);
  #pragma unroll
  for (int o = 0; o < 8; ++o) {
    int oc = ocg*8 + o;
    size_t base = (size_t)(b*128 + oc)*256 + ty*16 + tx;
    float m = m3[base] + acc[o] + bias[oc];
    float spk = (m >= 1.0f) ? 1.0f : 0.0f;
    m3[base] = m - spk;
    float s = spk * mf2[base];     // mask BEFORE pool (mask varies within 2x2)
    s += __shfl_xor(s, 1);
    s += __shfl_xor(s, 16);
    if (writer)
      p3[(size_t)b*8192 + oc*64 + (ty>>1)*8 + (tx>>1)] = s * 0.25f;
  }
}

// ---------------- fc1 (32x8192 @ 8192x1024^T) + LIF(c1) + mask_c1 ----------------
// grid 128: block = 8 units x 32 batch; thread = one (u,b) dot of 8192
__global__ __launch_bounds__(256) void k_fc1(const float* __restrict__ p3,
    const float* __restrict__ w, const float* __restrict__ bias,
    const float* __restrict__ mask, float* __restrict__ c1, float* __restrict__ sf1) {
  int t = threadIdx.x;
  int b  = t & 31;
  int ul = t >> 5;                       // 0..7
  int u = blockIdx.x * 8 + ul;
  const float4* wp = (const float4*)(w + (size_t)u * 8192);
  const float4* sp = (const float4*)(p3 + (size_t)b * 8192);
  float acc = 0.f;
  #pragma unroll 4
  for (int i = 0; i < 2048; ++i) {
    float4 a = wp[i];
    float4 s = sp[i];
    acc = fmaf(a.x, s.x, acc);
    acc = fmaf(a.y, s.y, acc);
    acc = fmaf(a.z, s.z, acc);
    acc = fmaf(a.w, s.w, acc);
  }
  int mi = b * 1024 + u;
  float m = c1[mi] + acc + bias[u];
  float spk = (m >= 1.0f) ? 1.0f : 0.0f;
  c1[mi] = m - spk;
  sf1[mi] = spk * mask[mi];
}

// ---------------- fc2 (32x1024 @ 1024x10^T) + LIF(c2) -> out ----------------
__global__ __launch_bounds__(256) void k_fc2(const float* __restrict__ sf1,
    const float* __restrict__ w, const float* __restrict__ bias,
    float* __restrict__ c2, float* __restrict__ out) {
  int idx = blockIdx.x * 256 + threadIdx.x;
  if (idx >= 320) return;
  int u = idx >> 5;      // 0..9
  int b = idx & 31;
  const float4* wp = (const float4*)(w + u * 1024);
  const float4* sp = (const float4*)(sf1 + b * 1024);
  float acc = 0.f;
  #pragma unroll 4
  for (int i = 0; i < 256; ++i) {
    float4 a = wp[i];
    float4 s = sp[i];
    acc = fmaf(a.x, s.x, acc);
    acc = fmaf(a.y, s.y, acc);
    acc = fmaf(a.z, s.z, acc);
    acc = fmaf(a.w, s.w, acc);
  }
  int mi = b * 10 + u;
  float m = c2[mi] + acc + bias[u];
  float spk = (m >= 1.0f) ? 1.0f : 0.0f;
  m -= spk;
  c2[mi] = m;
  out[mi] = m;   // final timestep's write is the answer
}

extern "C" void kernel_launch(void* const* d_in, const int* in_sizes, int n_in,
                              void* d_out, int out_size, void* d_ws, size_t ws_size,
                              hipStream_t stream) {
  const float* X   = (const float*)d_in[0];
  const float* w1  = (const float*)d_in[1];
  const float* b1  = (const float*)d_in[2];
  const float* w2  = (const float*)d_in[3];
  const float* b2  = (const float*)d_in[4];
  const float* w3  = (const float*)d_in[5];
  const float* b3  = (const float*)d_in[6];
  const float* fw1 = (const float*)d_in[7];
  const float* fb1 = (const float*)d_in[8];
  const float* fw2 = (const float*)d_in[9];
  const float* fb2 = (const float*)d_in[10];
  const float* mf1 = (const float*)d_in[11];
  const float* mf2 = (const float*)d_in[12];
  const float* mc1 = (const float*)d_in[13];
  float* out = (float*)d_out;

  float* ws  = (float*)d_ws;
  float* A1  = ws + OFF_A1;
  float* m1  = ws + OFF_M1;
  float* s1  = ws + OFF_S1;
  float* m2  = ws + OFF_M2;
  float* p2  = ws + OFF_P2;
  float* m3  = ws + OFF_M3;
  float* p3  = ws + OFF_P3;
  float* c1  = ws + OFF_C1;
  float* sf1 = ws + OFF_SF1;
  float* c2  = ws + OFF_C2;

  // ws is poisoned 0xAA before every timed call: zero all LIF state.
  hipMemsetAsync(m1, 0, (size_t)N_L1 * 4, stream);                       // m1
  hipMemsetAsync(m2, 0, (size_t)(N_M2 + N_P2 + N_M3) * 4, stream);       // m2,p2,m3
  hipMemsetAsync(c1, 0, (size_t)(2*N_C1 + N_C2) * 4, stream);            // c1,sf1,c2

  // conv1 output is timestep-invariant: compute once.
  k_conv1<<<N_L1/256, 256, 0, stream>>>(X, w1, b1, A1);

  for (int t = 0; t < T_STEPS; ++t) {
    k_lif1<<<N_L1/256, 256, 0, stream>>>(A1, mf1, m1, s1);
    k_conv2<<<512, 256, 0, stream>>>(s1, w2, b2, m2, p2);
    k_conv3<<<512, 256, 0, stream>>>(p2, w3, b3, mf2, m3, p3);
    k_fc1<<<128, 256, 0, stream>>>(p3, fw1, fb1, mc1, c1, sf1);
    k_fc2<<<2, 256, 0, stream>>>(sf1, fw2, fb2, c2, out);
  }
}

// Round 3
// 5404.341 us; speedup vs baseline: 1.0435x; 1.0435x over previous
//
#include <hip/hip_runtime.h>

#define T_STEPS 8

// ---- sizes (floats) ----
#define N_L1 (32*64*32*32)     // 2,097,152
#define N_M2 (32*128*32*32)    // 4,194,304
#define N_P2 (32*128*16*16)    // 1,048,576
#define N_M3 N_P2
#define N_P3 (32*8192)         // 262,144
#define N_C1 (32*1024)
#define N_C2 (32*10)

// ---- workspace offsets (floats) ----
#define OFF_A1  0
#define OFF_M1  (OFF_A1 + N_L1)
#define OFF_S1  (OFF_M1 + N_L1)
#define OFF_M2  (OFF_S1 + N_L1)
#define OFF_P2  (OFF_M2 + N_M2)
#define OFF_M3  (OFF_P2 + N_P2)
#define OFF_P3  (OFF_M3 + N_M3)
#define OFF_C1  (OFF_P3 + N_P3)
#define OFF_SF1 (OFF_C1 + N_C1)
#define OFF_C2  (OFF_SF1 + N_C1)

// ---------------- conv1 (runs once; X constant across timesteps) ----------------
__global__ __launch_bounds__(256) void k_conv1(const float* __restrict__ X,
    const float* __restrict__ w, const float* __restrict__ bias,
    float* __restrict__ A1) {
  int idx = blockIdx.x * 256 + threadIdx.x;          // (b,oc,y,x)
  int x = idx & 31, y = (idx >> 5) & 31, oc = (idx >> 10) & 63, b = idx >> 16;
  float acc = bias[oc];
  for (int ic = 0; ic < 3; ++ic) {
    const float* xp = X + (b*3 + ic)*1024;
    const float* wp = w + (oc*3 + ic)*9;
    #pragma unroll
    for (int dy = 0; dy < 3; ++dy) {
      int iy = y + dy - 1;
      if (iy < 0 || iy > 31) continue;
      #pragma unroll
      for (int dx = 0; dx < 3; ++dx) {
        int ix = x + dx - 1;
        if (ix < 0 || ix > 31) continue;
        acc = fmaf(xp[iy*32 + ix], wp[dy*3 + dx], acc);
      }
    }
  }
  A1[idx] = acc;
}

// ---------------- layer-1 LIF + dropout-mask (elementwise) ----------------
__global__ __launch_bounds__(256) void k_lif1(const float* __restrict__ A1,
    const float* __restrict__ mask, float* __restrict__ m1, float* __restrict__ s1) {
  int i = blockIdx.x * 256 + threadIdx.x;
  float m = m1[i] + A1[i];
  float spk = (m >= 1.0f) ? 1.0f : 0.0f;
  m1[i] = m - spk;
  s1[i] = spk * mask[i];
}

// ---------------- conv2 + LIF(m2) + 2x2 mean-pool ----------------
// grid 2048: b(32) x yt(4: 8-row bands) x ocg(16: 8 oc each)
// block 256 = 32(x) x 8(y); LDS input chunk 8 ic x 10 x 34 (stride 34 -> 2-way = free)
__global__ __launch_bounds__(256, 6) void k_conv2(const float* __restrict__ s1,
    const float* __restrict__ w, const float* __restrict__ bias,
    float* __restrict__ m2, float* __restrict__ p2) {
  int bid = blockIdx.x;
  int ocg = bid & 15;
  int yt  = (bid >> 4) & 3;
  int b   = bid >> 6;
  int t = threadIdx.x;
  int tx = t & 31, ty8 = t >> 5;          // wave = rows {2w, 2w+1} -> stride-34 2-way free

  __shared__ float lds[8 * 340];          // 8 ic x 10 x 34 = 10.6 KB
  float acc[8];
  #pragma unroll
  for (int o = 0; o < 8; ++o) acc[o] = 0.f;

  for (int chunk = 0; chunk < 8; ++chunk) {
    const float* src = s1 + (size_t)(b*64 + chunk*8) * 1024;
    __syncthreads();
    for (int i = t; i < 8*340; i += 256) {
      int ic = i / 340;
      int r  = i - ic*340;
      int ry = r / 34;
      int rx = r - ry*34;
      int iy = yt*8 + ry - 1;
      int ix = rx - 1;
      float v = 0.f;
      if ((unsigned)iy < 32u && (unsigned)ix < 32u)
        v = src[ic*1024 + iy*32 + ix];
      lds[i] = v;
    }
    __syncthreads();
    const float* wc = w + ((size_t)(ocg*8)*64 + chunk*8)*9;
    for (int ic = 0; ic < 8; ++ic) {
      float in9[9];
      #pragma unroll
      for (int dy = 0; dy < 3; ++dy)
        #pragma unroll
        for (int dx = 0; dx < 3; ++dx)
          in9[dy*3+dx] = lds[ic*340 + (ty8+dy)*34 + tx+dx];
      #pragma unroll
      for (int o = 0; o < 8; ++o) {
        const float* wp = wc + (o*64 + ic)*9;   // block-uniform -> s_load (18 KB set)
        #pragma unroll
        for (int k = 0; k < 9; ++k)
          acc[o] = fmaf(in9[k], wp[k], acc[o]);
      }
    }
  }

  // epilogue: bias + LIF + pool(spikes); same combine order as round 0 (x-pair then y-pair)
  int y = yt*8 + ty8, x = tx;
  bool writer = ((tx & 1) == 0) && ((ty8 & 1) == 0);
  #pragma unroll
  for (int o = 0; o < 8; ++o) {
    int oc = ocg*8 + o;
    size_t mi = (size_t)(b*128 + oc)*1024 + y*32 + x;
    float m = m2[mi] + acc[o] + bias[oc];
    float spk = (m >= 1.0f) ? 1.0f : 0.0f;
    m2[mi] = m - spk;
    float s = spk;
    s += __shfl_xor(s, 1);    // x-neighbor (lane bit0)
    s += __shfl_xor(s, 32);   // y-neighbor (ty8 bit0 = lane bit5)
    if (writer)
      p2[(size_t)(b*128 + oc)*256 + (y>>1)*16 + (x>>1)] = s * 0.25f;
  }
}

// ---------------- conv3 + LIF(m3) + mask_f2 + 2x2 mean-pool ----------------
// grid 1024: b(32) x ocg(32: 4 oc each); block 256 = 16x16 plane
// LDS input chunk 8 ic x 18 x 24 (stride 24: ty bank offs {0,24,16,8} -> exact 2-way, free)
__global__ __launch_bounds__(256, 4) void k_conv3(const float* __restrict__ p2,
    const float* __restrict__ w, const float* __restrict__ bias,
    const float* __restrict__ mf2, float* __restrict__ m3, float* __restrict__ p3) {
  int bid = blockIdx.x;
  int ocg = bid & 31;
  int b   = bid >> 5;
  int t = threadIdx.x;
  int tx = t & 15, ty = t >> 4;

  __shared__ float lds[8 * 432];          // 8 ic x 18 x 24 = 13.5 KB
  float acc[4];
  #pragma unroll
  for (int o = 0; o < 4; ++o) acc[o] = 0.f;

  for (int chunk = 0; chunk < 16; ++chunk) {
    const float* src = p2 + (size_t)(b*128 + chunk*8) * 256;
    __syncthreads();
    for (int i = t; i < 8*432; i += 256) {
      int ic = i / 432;
      int r  = i - ic*432;
      int ry = r / 24;
      int rx = r - ry*24;
      if (rx < 18) {
        int iy = ry - 1;
        int ix = rx - 1;
        float v = 0.f;
        if ((unsigned)iy < 16u && (unsigned)ix < 16u)
          v = src[ic*256 + iy*16 + ix];
        lds[i] = v;
      }
    }
    __syncthreads();
    const float* wc = w + ((size_t)(ocg*4)*128 + chunk*8)*9;
    for (int ic = 0; ic < 8; ++ic) {
      float in9[9];
      #pragma unroll
      for (int dy = 0; dy < 3; ++dy)
        #pragma unroll
        for (int dx = 0; dx < 3; ++dx)
          in9[dy*3+dx] = lds[ic*432 + (ty+dy)*24 + tx+dx];
      #pragma unroll
      for (int o = 0; o < 4; ++o) {
        const float* wp = wc + (o*128 + ic)*9;  // block-uniform -> s_load (18 KB set)
        #pragma unroll
        for (int k = 0; k < 9; ++k)
          acc[o] = fmaf(in9[k], wp[k], acc[o]);
      }
    }
  }

  bool writer = ((tx & 1) == 0) && ((ty & 1) == 0);
  #pragma unroll
  for (int o = 0; o < 4; ++o) {
    int oc = ocg*4 + o;
    size_t base = (size_t)(b*128 + oc)*256 + ty*16 + tx;
    float m = m3[base] + acc[o] + bias[oc];
    float spk = (m >= 1.0f) ? 1.0f : 0.0f;
    m3[base] = m - spk;
    float s = spk * mf2[base];     // mask BEFORE pool (mask varies within 2x2)
    s += __shfl_xor(s, 1);
    s += __shfl_xor(s, 16);
    if (writer)
      p3[(size_t)b*8192 + oc*64 + (ty>>1)*8 + (tx>>1)] = s * 0.25f;
  }
}

// ---------------- fc1 (32x8192 @ 8192x1024^T) + LIF(c1) + mask_c1 ----------------
// order-preserving sequential dot per (u,b); revisit with its own profile line
__global__ __launch_bounds__(256) void k_fc1(const float* __restrict__ p3,
    const float* __restrict__ w, const float* __restrict__ bias,
    const float* __restrict__ mask, float* __restrict__ c1, float* __restrict__ sf1) {
  int t = threadIdx.x;
  int b  = t & 31;
  int ul = t >> 5;                       // 0..7
  int u = blockIdx.x * 8 + ul;
  const float4* wp = (const float4*)(w + (size_t)u * 8192);
  const float4* sp = (const float4*)(p3 + (size_t)b * 8192);
  float acc = 0.f;
  #pragma unroll 8
  for (int i = 0; i < 2048; ++i) {
    float4 a = wp[i];
    float4 s = sp[i];
    acc = fmaf(a.x, s.x, acc);
    acc = fmaf(a.y, s.y, acc);
    acc = fmaf(a.z, s.z, acc);
    acc = fmaf(a.w, s.w, acc);
  }
  int mi = b * 1024 + u;
  float m = c1[mi] + acc + bias[u];
  float spk = (m >= 1.0f) ? 1.0f : 0.0f;
  c1[mi] = m - spk;
  sf1[mi] = spk * mask[mi];
}

// ---------------- fc2 (32x1024 @ 1024x10^T) + LIF(c2) -> out ----------------
__global__ __launch_bounds__(256) void k_fc2(const float* __restrict__ sf1,
    const float* __restrict__ w, const float* __restrict__ bias,
    float* __restrict__ c2, float* __restrict__ out) {
  int idx = blockIdx.x * 256 + threadIdx.x;
  if (idx >= 320) return;
  int u = idx >> 5;      // 0..9
  int b = idx & 31;
  const float4* wp = (const float4*)(w + u * 1024);
  const float4* sp = (const float4*)(sf1 + b * 1024);
  float acc = 0.f;
  #pragma unroll 4
  for (int i = 0; i < 256; ++i) {
    float4 a = wp[i];
    float4 s = sp[i];
    acc = fmaf(a.x, s.x, acc);
    acc = fmaf(a.y, s.y, acc);
    acc = fmaf(a.z, s.z, acc);
    acc = fmaf(a.w, s.w, acc);
  }
  int mi = b * 10 + u;
  float m = c2[mi] + acc + bias[u];
  float spk = (m >= 1.0f) ? 1.0f : 0.0f;
  m -= spk;
  c2[mi] = m;
  out[mi] = m;   // final timestep's write is the answer
}

extern "C" void kernel_launch(void* const* d_in, const int* in_sizes, int n_in,
                              void* d_out, int out_size, void* d_ws, size_t ws_size,
                              hipStream_t stream) {
  const float* X   = (const float*)d_in[0];
  const float* w1  = (const float*)d_in[1];
  const float* b1  = (const float*)d_in[2];
  const float* w2  = (const float*)d_in[3];
  const float* b2  = (const float*)d_in[4];
  const float* w3  = (const float*)d_in[5];
  const float* b3  = (const float*)d_in[6];
  const float* fw1 = (const float*)d_in[7];
  const float* fb1 = (const float*)d_in[8];
  const float* fw2 = (const float*)d_in[9];
  const float* fb2 = (const float*)d_in[10];
  const float* mf1 = (const float*)d_in[11];
  const float* mf2 = (const float*)d_in[12];
  const float* mc1 = (const float*)d_in[13];
  float* out = (float*)d_out;

  float* ws  = (float*)d_ws;
  float* A1  = ws + OFF_A1;
  float* m1  = ws + OFF_M1;
  float* s1  = ws + OFF_S1;
  float* m2  = ws + OFF_M2;
  float* p2  = ws + OFF_P2;
  float* m3  = ws + OFF_M3;
  float* p3  = ws + OFF_P3;
  float* c1  = ws + OFF_C1;
  float* sf1 = ws + OFF_SF1;
  float* c2  = ws + OFF_C2;

  // ws is poisoned 0xAA before every timed call: zero all LIF state.
  hipMemsetAsync(m1, 0, (size_t)N_L1 * 4, stream);                       // m1
  hipMemsetAsync(m2, 0, (size_t)(N_M2 + N_P2 + N_M3) * 4, stream);       // m2,p2,m3
  hipMemsetAsync(c1, 0, (size_t)(2*N_C1 + N_C2) * 4, stream);            // c1,sf1,c2

  // conv1 output is timestep-invariant: compute once.
  k_conv1<<<N_L1/256, 256, 0, stream>>>(X, w1, b1, A1);

  for (int t = 0; t < T_STEPS; ++t) {
    k_lif1<<<N_L1/256, 256, 0, stream>>>(A1, mf1, m1, s1);
    k_conv2<<<2048, 256, 0, stream>>>(s1, w2, b2, m2, p2);
    k_conv3<<<1024, 256, 0, stream>>>(p2, w3, b3, mf2, m3, p3);
    k_fc1<<<128, 256, 0, stream>>>(p3, fw1, fb1, mc1, c1, sf1);
    k_fc2<<<2, 256, 0, stream>>>(sf1, fw2, fb2, c2, out);
  }
}

// Round 4
// 4379.516 us; speedup vs baseline: 1.2877x; 1.2340x over previous
//
#include <hip/hip_runtime.h>

#define T_STEPS 8

// ---- sizes (floats) ----
#define N_L1 (32*64*32*32)     // 2,097,152
#define N_M2 (32*128*32*32)    // 4,194,304
#define N_P2 (32*128*16*16)    // 1,048,576
#define N_M3 N_P2
#define N_P3 (32*8192)         // 262,144
#define N_C1 (32*1024)
#define N_C2 (32*10)
#define N_WT (2048*1024*4)     // transposed fc1 weights (8,388,608 floats)

// ---- workspace offsets (floats) ----
#define OFF_A1  0
#define OFF_M1  (OFF_A1 + N_L1)
#define OFF_S1  (OFF_M1 + N_L1)
#define OFF_M2  (OFF_S1 + N_L1)
#define OFF_P2  (OFF_M2 + N_M2)
#define OFF_M3  (OFF_P2 + N_P2)
#define OFF_P3  (OFF_M3 + N_M3)
#define OFF_C1  (OFF_P3 + N_P3)
#define OFF_SF1 (OFF_C1 + N_C1)
#define OFF_C2  (OFF_SF1 + N_C1)
#define OFF_WT  (OFF_C2 + N_C2)       // multiple of 4 -> float4-aligned

// ---------------- conv1 (runs once; X constant across timesteps) ----------------
__global__ __launch_bounds__(256) void k_conv1(const float* __restrict__ X,
    const float* __restrict__ w, const float* __restrict__ bias,
    float* __restrict__ A1) {
  int idx = blockIdx.x * 256 + threadIdx.x;          // (b,oc,y,x)
  int x = idx & 31, y = (idx >> 5) & 31, oc = (idx >> 10) & 63, b = idx >> 16;
  float acc = bias[oc];
  for (int ic = 0; ic < 3; ++ic) {
    const float* xp = X + (b*3 + ic)*1024;
    const float* wp = w + (oc*3 + ic)*9;
    #pragma unroll
    for (int dy = 0; dy < 3; ++dy) {
      int iy = y + dy - 1;
      if (iy < 0 || iy > 31) continue;
      #pragma unroll
      for (int dx = 0; dx < 3; ++dx) {
        int ix = x + dx - 1;
        if (ix < 0 || ix > 31) continue;
        acc = fmaf(xp[iy*32 + ix], wp[dy*3 + dx], acc);
      }
    }
  }
  A1[idx] = acc;
}

// ---------------- layer-1 LIF + dropout-mask (elementwise) ----------------
__global__ __launch_bounds__(256) void k_lif1(const float* __restrict__ A1,
    const float* __restrict__ mask, float* __restrict__ m1, float* __restrict__ s1) {
  int i = blockIdx.x * 256 + threadIdx.x;
  float m = m1[i] + A1[i];
  float spk = (m >= 1.0f) ? 1.0f : 0.0f;
  m1[i] = m - spk;
  s1[i] = spk * mask[i];
}

// ---------------- conv2 + LIF(m2) + 2x2 mean-pool ----------------
// grid 2048: b(32) x yt(4: 8-row bands) x ocg(16: 8 oc each)
// block 256 = 32(x) x 8(y); LDS input chunk 8 ic x 10 x 34 (stride 34 -> 2-way = free)
__global__ __launch_bounds__(256, 6) void k_conv2(const float* __restrict__ s1,
    const float* __restrict__ w, const float* __restrict__ bias,
    float* __restrict__ m2, float* __restrict__ p2) {
  int bid = blockIdx.x;
  int ocg = bid & 15;
  int yt  = (bid >> 4) & 3;
  int b   = bid >> 6;
  int t = threadIdx.x;
  int tx = t & 31, ty8 = t >> 5;          // wave = rows {2w, 2w+1} -> stride-34 2-way free

  __shared__ float lds[8 * 340];          // 8 ic x 10 x 34 = 10.6 KB
  float acc[8];
  #pragma unroll
  for (int o = 0; o < 8; ++o) acc[o] = 0.f;

  for (int chunk = 0; chunk < 8; ++chunk) {
    const float* src = s1 + (size_t)(b*64 + chunk*8) * 1024;
    __syncthreads();
    for (int i = t; i < 8*340; i += 256) {
      int ic = i / 340;
      int r  = i - ic*340;
      int ry = r / 34;
      int rx = r - ry*34;
      int iy = yt*8 + ry - 1;
      int ix = rx - 1;
      float v = 0.f;
      if ((unsigned)iy < 32u && (unsigned)ix < 32u)
        v = src[ic*1024 + iy*32 + ix];
      lds[i] = v;
    }
    __syncthreads();
    const float* wc = w + ((size_t)(ocg*8)*64 + chunk*8)*9;
    for (int ic = 0; ic < 8; ++ic) {
      float in9[9];
      #pragma unroll
      for (int dy = 0; dy < 3; ++dy)
        #pragma unroll
        for (int dx = 0; dx < 3; ++dx)
          in9[dy*3+dx] = lds[ic*340 + (ty8+dy)*34 + tx+dx];
      #pragma unroll
      for (int o = 0; o < 8; ++o) {
        const float* wp = wc + (o*64 + ic)*9;   // block-uniform -> s_load (18 KB set)
        #pragma unroll
        for (int k = 0; k < 9; ++k)
          acc[o] = fmaf(in9[k], wp[k], acc[o]);
      }
    }
  }

  // epilogue: bias + LIF + pool(spikes); same combine order as round 0 (x-pair then y-pair)
  int y = yt*8 + ty8, x = tx;
  bool writer = ((tx & 1) == 0) && ((ty8 & 1) == 0);
  #pragma unroll
  for (int o = 0; o < 8; ++o) {
    int oc = ocg*8 + o;
    size_t mi = (size_t)(b*128 + oc)*1024 + y*32 + x;
    float m = m2[mi] + acc[o] + bias[oc];
    float spk = (m >= 1.0f) ? 1.0f : 0.0f;
    m2[mi] = m - spk;
    float s = spk;
    s += __shfl_xor(s, 1);    // x-neighbor (lane bit0)
    s += __shfl_xor(s, 32);   // y-neighbor (ty8 bit0 = lane bit5)
    if (writer)
      p2[(size_t)(b*128 + oc)*256 + (y>>1)*16 + (x>>1)] = s * 0.25f;
  }
}

// ---------------- conv3 + LIF(m3) + mask_f2 + 2x2 mean-pool ----------------
// grid 1024: b(32) x ocg(32: 4 oc each); block 256 = 16x16 plane
// LDS input chunk 8 ic x 18 x 24 (stride 24: ty bank offs {0,24,16,8} -> exact 2-way, free)
__global__ __launch_bounds__(256, 4) void k_conv3(const float* __restrict__ p2,
    const float* __restrict__ w, const float* __restrict__ bias,
    const float* __restrict__ mf2, float* __restrict__ m3, float* __restrict__ p3) {
  int bid = blockIdx.x;
  int ocg = bid & 31;
  int b   = bid >> 5;
  int t = threadIdx.x;
  int tx = t & 15, ty = t >> 4;

  __shared__ float lds[8 * 432];          // 8 ic x 18 x 24 = 13.5 KB
  float acc[4];
  #pragma unroll
  for (int o = 0; o < 4; ++o) acc[o] = 0.f;

  for (int chunk = 0; chunk < 16; ++chunk) {
    const float* src = p2 + (size_t)(b*128 + chunk*8) * 256;
    __syncthreads();
    for (int i = t; i < 8*432; i += 256) {
      int ic = i / 432;
      int r  = i - ic*432;
      int ry = r / 24;
      int rx = r - ry*24;
      if (rx < 18) {
        int iy = ry - 1;
        int ix = rx - 1;
        float v = 0.f;
        if ((unsigned)iy < 16u && (unsigned)ix < 16u)
          v = src[ic*256 + iy*16 + ix];
        lds[i] = v;
      }
    }
    __syncthreads();
    const float* wc = w + ((size_t)(ocg*4)*128 + chunk*8)*9;
    for (int ic = 0; ic < 8; ++ic) {
      float in9[9];
      #pragma unroll
      for (int dy = 0; dy < 3; ++dy)
        #pragma unroll
        for (int dx = 0; dx < 3; ++dx)
          in9[dy*3+dx] = lds[ic*432 + (ty+dy)*24 + tx+dx];
      #pragma unroll
      for (int o = 0; o < 4; ++o) {
        const float* wp = wc + (o*128 + ic)*9;  // block-uniform -> s_load (18 KB set)
        #pragma unroll
        for (int k = 0; k < 9; ++k)
          acc[o] = fmaf(in9[k], wp[k], acc[o]);
      }
    }
  }

  bool writer = ((tx & 1) == 0) && ((ty & 1) == 0);
  #pragma unroll
  for (int o = 0; o < 4; ++o) {
    int oc = ocg*4 + o;
    size_t base = (size_t)(b*128 + oc)*256 + ty*16 + tx;
    float m = m3[base] + acc[o] + bias[oc];
    float spk = (m >= 1.0f) ? 1.0f : 0.0f;
    m3[base] = m - spk;
    float s = spk * mf2[base];     // mask BEFORE pool (mask varies within 2x2)
    s += __shfl_xor(s, 1);
    s += __shfl_xor(s, 16);
    if (writer)
      p3[(size_t)b*8192 + oc*64 + (ty>>1)*8 + (tx>>1)] = s * 0.25f;
  }
}

// ---------------- fc1 weight transpose (runs once) ----------------
// w[1024][8192] viewed as w4[1024][2048] float4  ->  wt4[2048][1024] float4
// tile 32x32 float4 via LDS; all global accesses coalesced.
__global__ __launch_bounds__(256) void k_wt(const float* __restrict__ w,
    float* __restrict__ wt) {
  const float4* w4 = (const float4*)w;
  float4* wt4 = (float4*)wt;
  int kt = blockIdx.x & 63;          // k4-tile (2048/32)
  int ut = blockIdx.x >> 6;          // u-tile  (1024/32)
  __shared__ float4 tile[32][33];
  int t = threadIdx.x;
  for (int i = t; i < 1024; i += 256) {
    int r = i >> 5, c = i & 31;      // r = u_local, c = k4_local (coalesced read)
    tile[r][c] = w4[(size_t)(ut*32 + r)*2048 + kt*32 + c];
  }
  __syncthreads();
  for (int i = t; i < 1024; i += 256) {
    int r = i >> 5, c = i & 31;      // r = k4_local, c = u_local (coalesced write)
    wt4[(size_t)(kt*32 + r)*1024 + ut*32 + c] = tile[c][r];
  }
}

// ---------------- fc1 v3: tiled, order-preserving ----------------
// grid 256 = ug(128: 8 u each) x bg(2: 16 b each); block 128 = 8 u-lanes x 16 b
// w: coalesced 128B wave reads from wt4 (u-major), redundancy 2x (64 MB/step, L3).
// s: staged in LDS, broadcast reads (stride 129 -> banks 4b..4b+3, conflict-free).
// Accumulation: single FMA chain, k ascending -> bit-identical to v2.
__global__ __launch_bounds__(128) void k_fc1v3(const float* __restrict__ p3,
    const float* __restrict__ wt, const float* __restrict__ bias,
    const float* __restrict__ mask, float* __restrict__ c1, float* __restrict__ sf1) {
  const float4* wt4 = (const float4*)wt;
  const float4* p34 = (const float4*)p3;
  int ug = blockIdx.x >> 1;
  int bg = blockIdx.x & 1;
  int u0 = ug * 8, b0 = bg * 16;
  int t = threadIdx.x;
  int u_l = t & 7, b_sub = t >> 3;   // wave0: b_sub 0..7, wave1: 8..15

  __shared__ float4 sld[16 * 129];   // 16 b rows x 128 k4, pad->129 (33 KB)
  float acc = 0.f;

  for (int kc = 0; kc < 16; ++kc) {
    __syncthreads();
    for (int j = t; j < 16*128; j += 128) {
      int b_i = j >> 7, k4_i = j & 127;
      sld[b_i*129 + k4_i] = p34[(size_t)(b0 + b_i)*2048 + kc*128 + k4_i];
    }
    __syncthreads();
    const float4* wp = wt4 + (size_t)(kc*128)*1024 + u0 + u_l;
    const float4* sp = sld + b_sub*129;
    #pragma unroll 8
    for (int k4 = 0; k4 < 128; ++k4) {
      float4 wv = wp[(size_t)k4 * 1024];
      float4 sv = sp[k4];
      acc = fmaf(wv.x, sv.x, acc);
      acc = fmaf(wv.y, sv.y, acc);
      acc = fmaf(wv.z, sv.z, acc);
      acc = fmaf(wv.w, sv.w, acc);
    }
  }

  int u = u0 + u_l, b = b0 + b_sub;
  int mi = b * 1024 + u;
  float m = c1[mi] + acc + bias[u];
  float spk = (m >= 1.0f) ? 1.0f : 0.0f;
  c1[mi] = m - spk;
  sf1[mi] = spk * mask[mi];
}

// ---------------- fc1 fallback (ws too small for transpose) ----------------
__global__ __launch_bounds__(256) void k_fc1(const float* __restrict__ p3,
    const float* __restrict__ w, const float* __restrict__ bias,
    const float* __restrict__ mask, float* __restrict__ c1, float* __restrict__ sf1) {
  int t = threadIdx.x;
  int b  = t & 31;
  int ul = t >> 5;
  int u = blockIdx.x * 8 + ul;
  const float4* wp = (const float4*)(w + (size_t)u * 8192);
  const float4* sp = (const float4*)(p3 + (size_t)b * 8192);
  float acc = 0.f;
  #pragma unroll 8
  for (int i = 0; i < 2048; ++i) {
    float4 a = wp[i];
    float4 s = sp[i];
    acc = fmaf(a.x, s.x, acc);
    acc = fmaf(a.y, s.y, acc);
    acc = fmaf(a.z, s.z, acc);
    acc = fmaf(a.w, s.w, acc);
  }
  int mi = b * 1024 + u;
  float m = c1[mi] + acc + bias[u];
  float spk = (m >= 1.0f) ? 1.0f : 0.0f;
  c1[mi] = m - spk;
  sf1[mi] = spk * mask[mi];
}

// ---------------- fc2 (32x1024 @ 1024x10^T) + LIF(c2) -> out ----------------
__global__ __launch_bounds__(256) void k_fc2(const float* __restrict__ sf1,
    const float* __restrict__ w, const float* __restrict__ bias,
    float* __restrict__ c2, float* __restrict__ out) {
  int idx = blockIdx.x * 256 + threadIdx.x;
  if (idx >= 320) return;
  int u = idx >> 5;      // 0..9
  int b = idx & 31;
  const float4* wp = (const float4*)(w + u * 1024);
  const float4* sp = (const float4*)(sf1 + b * 1024);
  float acc = 0.f;
  #pragma unroll 4
  for (int i = 0; i < 256; ++i) {
    float4 a = wp[i];
    float4 s = sp[i];
    acc = fmaf(a.x, s.x, acc);
    acc = fmaf(a.y, s.y, acc);
    acc = fmaf(a.z, s.z, acc);
    acc = fmaf(a.w, s.w, acc);
  }
  int mi = b * 10 + u;
  float m = c2[mi] + acc + bias[u];
  float spk = (m >= 1.0f) ? 1.0f : 0.0f;
  m -= spk;
  c2[mi] = m;
  out[mi] = m;   // final timestep's write is the answer
}

extern "C" void kernel_launch(void* const* d_in, const int* in_sizes, int n_in,
                              void* d_out, int out_size, void* d_ws, size_t ws_size,
                              hipStream_t stream) {
  const float* X   = (const float*)d_in[0];
  const float* w1  = (const float*)d_in[1];
  const float* b1  = (const float*)d_in[2];
  const float* w2  = (const float*)d_in[3];
  const float* b2  = (const float*)d_in[4];
  const float* w3  = (const float*)d_in[5];
  const float* b3  = (const float*)d_in[6];
  const float* fw1 = (const float*)d_in[7];
  const float* fb1 = (const float*)d_in[8];
  const float* fw2 = (const float*)d_in[9];
  const float* fb2 = (const float*)d_in[10];
  const float* mf1 = (const float*)d_in[11];
  const float* mf2 = (const float*)d_in[12];
  const float* mc1 = (const float*)d_in[13];
  float* out = (float*)d_out;

  float* ws  = (float*)d_ws;
  float* A1  = ws + OFF_A1;
  float* m1  = ws + OFF_M1;
  float* s1  = ws + OFF_S1;
  float* m2  = ws + OFF_M2;
  float* p2  = ws + OFF_P2;
  float* m3  = ws + OFF_M3;
  float* p3  = ws + OFF_P3;
  float* c1  = ws + OFF_C1;
  float* sf1 = ws + OFF_SF1;
  float* c2  = ws + OFF_C2;
  float* wt  = ws + OFF_WT;

  const bool use_wt = ws_size >= ((size_t)OFF_WT + N_WT) * 4;  // constant per run

  // ws is poisoned 0xAA before every timed call: zero all LIF state.
  hipMemsetAsync(m1, 0, (size_t)N_L1 * 4, stream);                       // m1
  hipMemsetAsync(m2, 0, (size_t)(N_M2 + N_P2 + N_M3) * 4, stream);       // m2,p2,m3
  hipMemsetAsync(c1, 0, (size_t)(2*N_C1 + N_C2) * 4, stream);            // c1,sf1,c2

  // conv1 output is timestep-invariant: compute once.
  k_conv1<<<N_L1/256, 256, 0, stream>>>(X, w1, b1, A1);
  if (use_wt)
    k_wt<<<2048, 256, 0, stream>>>(fw1, wt);                             // once

  for (int t = 0; t < T_STEPS; ++t) {
    k_lif1<<<N_L1/256, 256, 0, stream>>>(A1, mf1, m1, s1);
    k_conv2<<<2048, 256, 0, stream>>>(s1, w2, b2, m2, p2);
    k_conv3<<<1024, 256, 0, stream>>>(p2, w3, b3, mf2, m3, p3);
    if (use_wt)
      k_fc1v3<<<256, 128, 0, stream>>>(p3, wt, fb1, mc1, c1, sf1);
    else
      k_fc1<<<128, 256, 0, stream>>>(p3, fw1, fb1, mc1, c1, sf1);
    k_fc2<<<2, 256, 0, stream>>>(sf1, fw2, fb2, c2, out);
  }
}

// Round 6
// 3874.065 us; speedup vs baseline: 1.4557x; 1.1305x over previous
//
#include <hip/hip_runtime.h>

#define T_STEPS 8

// ---- sizes (floats) ----
#define N_L1 (32*64*32*32)     // 2,097,152
#define N_M2 (32*128*32*32)    // 4,194,304
#define N_P2 (32*128*16*16)    // 1,048,576
#define N_M3 N_P2
#define N_P3 (32*8192)         // 262,144
#define N_C1 (32*1024)
#define N_C2 (32*10)
#define N_WT (2048*1024*4)     // transposed fc1 weights (8,388,608 floats)

// ---- workspace offsets (floats) ----
#define OFF_A1  0
#define OFF_M1  (OFF_A1 + N_L1)
#define OFF_S1  (OFF_M1 + N_L1)
#define OFF_M2  (OFF_S1 + N_L1)
#define OFF_P2  (OFF_M2 + N_M2)
#define OFF_M3  (OFF_P2 + N_P2)
#define OFF_P3  (OFF_M3 + N_M3)
#define OFF_C1  (OFF_P3 + N_P3)
#define OFF_SF1 (OFF_C1 + N_C1)
#define OFF_C2  (OFF_SF1 + N_C1)
#define OFF_WT  (OFF_C2 + N_C2)       // multiple of 4 -> float4-aligned

// ---------------- conv1 (runs once; X constant across timesteps) ----------------
__global__ __launch_bounds__(256) void k_conv1(const float* __restrict__ X,
    const float* __restrict__ w, const float* __restrict__ bias,
    float* __restrict__ A1) {
  int idx = blockIdx.x * 256 + threadIdx.x;          // (b,oc,y,x)
  int x = idx & 31, y = (idx >> 5) & 31, oc = (idx >> 10) & 63, b = idx >> 16;
  float acc = bias[oc];
  for (int ic = 0; ic < 3; ++ic) {
    const float* xp = X + (b*3 + ic)*1024;
    const float* wp = w + (oc*3 + ic)*9;
    #pragma unroll
    for (int dy = 0; dy < 3; ++dy) {
      int iy = y + dy - 1;
      if (iy < 0 || iy > 31) continue;
      #pragma unroll
      for (int dx = 0; dx < 3; ++dx) {
        int ix = x + dx - 1;
        if (ix < 0 || ix > 31) continue;
        acc = fmaf(xp[iy*32 + ix], wp[dy*3 + dx], acc);
      }
    }
  }
  A1[idx] = acc;
}

// ---------------- layer-1 LIF + dropout-mask (elementwise) ----------------
__global__ __launch_bounds__(256) void k_lif1(const float* __restrict__ A1,
    const float* __restrict__ mask, float* __restrict__ m1, float* __restrict__ s1) {
  int i = blockIdx.x * 256 + threadIdx.x;
  float m = m1[i] + A1[i];
  float spk = (m >= 1.0f) ? 1.0f : 0.0f;
  m1[i] = m - spk;
  s1[i] = spk * mask[i];
}

// ---------------- conv2 + LIF(m2) + 2x2 mean-pool (v3: 2x register tile) ----------------
// grid 1024: b(32) x yt(2: 16-row bands) x ocg(16: 8 oc each)
// block 256 = 16 xpair x 16 y; per thread: 2 x-outputs x 8 oc (16 acc)
// LDS chunk 8 ic x 18 x 34; per-ic reads are 3x aligned 4-float rows -> ds_read_b64 pairs
__global__ __launch_bounds__(256, 4) void k_conv2(const float* __restrict__ s1,
    const float* __restrict__ w, const float* __restrict__ bias,
    float* __restrict__ m2, float* __restrict__ p2) {
  int bid = blockIdx.x;
  int ocg = bid & 15;
  int yt  = (bid >> 4) & 1;
  int b   = bid >> 5;
  int t = threadIdx.x;
  int xp = t & 15, ty = t >> 4;           // x = {2xp, 2xp+1}, row = ty (0..15)

  __shared__ float lds[8 * 612];          // 8 ic x 18 rows x 34 cols = 19.6 KB
  float acc[2][8];
  #pragma unroll
  for (int o = 0; o < 8; ++o) { acc[0][o] = 0.f; acc[1][o] = 0.f; }

  for (int chunk = 0; chunk < 8; ++chunk) {
    const float* src = s1 + (size_t)(b*64 + chunk*8) * 1024;
    __syncthreads();
    #pragma unroll
    for (int ic = 0; ic < 8; ++ic) {
      for (int j = t; j < 612; j += 256) {
        int ry = j / 34;
        int rx = j - ry*34;
        int iy = yt*16 + ry - 1;
        int ix = rx - 1;
        float v = 0.f;
        if ((unsigned)iy < 32u && (unsigned)ix < 32u)
          v = src[ic*1024 + iy*32 + ix];
        lds[ic*612 + j] = v;
      }
    }
    __syncthreads();
    const float* wc = w + ((size_t)(ocg*8)*64 + chunk*8)*9;
    for (int ic = 0; ic < 8; ++ic) {
      float in12[12];
      const float* lp = &lds[ic*612 + ty*34 + 2*xp];   // 8B-aligned rows of 4
      #pragma unroll
      for (int dy = 0; dy < 3; ++dy)
        #pragma unroll
        for (int dx = 0; dx < 4; ++dx)
          in12[dy*4+dx] = lp[dy*34 + dx];
      #pragma unroll
      for (int o = 0; o < 8; ++o) {
        const float* wp = wc + (o*64 + ic)*9;   // block-uniform -> s_load (18 KB set)
        #pragma unroll
        for (int k = 0; k < 9; ++k) {
          const int dy = k/3, dx = k - 3*(k/3);  // compile-time
          acc[0][o] = fmaf(in12[dy*4+dx],   wp[k], acc[0][o]);
          acc[1][o] = fmaf(in12[dy*4+dx+1], wp[k], acc[1][o]);
        }
      }
    }
  }

  // epilogue: bias + LIF + pool; x-pair summed in-thread (same order s00+s01),
  // y-pair via shfl (ty bit0 = lane bit4), then ((s00+s01)+(s10+s11))*0.25 as before
  int y = yt*16 + ty;
  int x0 = 2*xp;
  bool ywriter = ((ty & 1) == 0);
  #pragma unroll
  for (int o = 0; o < 8; ++o) {
    int oc = ocg*8 + o;
    size_t mi = (size_t)(b*128 + oc)*1024 + y*32 + x0;
    float2 mv = *(const float2*)&m2[mi];
    float ma = mv.x + acc[0][o] + bias[oc];
    float mb = mv.y + acc[1][o] + bias[oc];
    float sa = (ma >= 1.0f) ? 1.0f : 0.0f;
    float sb = (mb >= 1.0f) ? 1.0f : 0.0f;
    float2 mo; mo.x = ma - sa; mo.y = mb - sb;
    *(float2*)&m2[mi] = mo;
    float s = sa + sb;
    s += __shfl_xor(s, 16);
    if (ywriter)
      p2[(size_t)(b*128 + oc)*256 + (y>>1)*16 + xp] = s * 0.25f;
  }
}

// ---------------- conv3 + LIF(m3) + mask_f2 + 2x2 mean-pool ----------------
// grid 1024: b(32) x ocg(32: 4 oc each); block 256 = 16x16 plane
// LDS input chunk 8 ic x 18 x 24 (stride 24: ty bank offs {0,24,16,8} -> exact 2-way, free)
__global__ __launch_bounds__(256, 4) void k_conv3(const float* __restrict__ p2,
    const float* __restrict__ w, const float* __restrict__ bias,
    const float* __restrict__ mf2, float* __restrict__ m3, float* __restrict__ p3) {
  int bid = blockIdx.x;
  int ocg = bid & 31;
  int b   = bid >> 5;
  int t = threadIdx.x;
  int tx = t & 15, ty = t >> 4;

  __shared__ float lds[8 * 432];          // 8 ic x 18 x 24 = 13.5 KB
  float acc[4];
  #pragma unroll
  for (int o = 0; o < 4; ++o) acc[o] = 0.f;

  for (int chunk = 0; chunk < 16; ++chunk) {
    const float* src = p2 + (size_t)(b*128 + chunk*8) * 256;
    __syncthreads();
    for (int i = t; i < 8*432; i += 256) {
      int ic = i / 432;
      int r  = i - ic*432;
      int ry = r / 24;
      int rx = r - ry*24;
      if (rx < 18) {
        int iy = ry - 1;
        int ix = rx - 1;
        float v = 0.f;
        if ((unsigned)iy < 16u && (unsigned)ix < 16u)
          v = src[ic*256 + iy*16 + ix];
        lds[i] = v;
      }
    }
    __syncthreads();
    const float* wc = w + ((size_t)(ocg*4)*128 + chunk*8)*9;
    for (int ic = 0; ic < 8; ++ic) {
      float in9[9];
      #pragma unroll
      for (int dy = 0; dy < 3; ++dy)
        #pragma unroll
        for (int dx = 0; dx < 3; ++dx)
          in9[dy*3+dx] = lds[ic*432 + (ty+dy)*24 + tx+dx];
      #pragma unroll
      for (int o = 0; o < 4; ++o) {
        const float* wp = wc + (o*128 + ic)*9;  // block-uniform -> s_load (18 KB set)
        #pragma unroll
        for (int k = 0; k < 9; ++k)
          acc[o] = fmaf(in9[k], wp[k], acc[o]);
      }
    }
  }

  bool writer = ((tx & 1) == 0) && ((ty & 1) == 0);
  #pragma unroll
  for (int o = 0; o < 4; ++o) {
    int oc = ocg*4 + o;
    size_t base = (size_t)(b*128 + oc)*256 + ty*16 + tx;
    float m = m3[base] + acc[o] + bias[oc];
    float spk = (m >= 1.0f) ? 1.0f : 0.0f;
    m3[base] = m - spk;
    float s = spk * mf2[base];     // mask BEFORE pool (mask varies within 2x2)
    s += __shfl_xor(s, 1);
    s += __shfl_xor(s, 16);
    if (writer)
      p3[(size_t)b*8192 + oc*64 + (ty>>1)*8 + (tx>>1)] = s * 0.25f;
  }
}

// ---------------- fc1 weight transpose (runs once) ----------------
// w[1024][8192] viewed as w4[1024][2048] float4  ->  wt4[2048][1024] float4
__global__ __launch_bounds__(256) void k_wt(const float* __restrict__ w,
    float* __restrict__ wt) {
  const float4* w4 = (const float4*)w;
  float4* wt4 = (float4*)wt;
  int kt = blockIdx.x & 63;          // k4-tile (2048/32)
  int ut = blockIdx.x >> 6;          // u-tile  (1024/32)
  __shared__ float4 tile[32][33];
  int t = threadIdx.x;
  for (int i = t; i < 1024; i += 256) {
    int r = i >> 5, c = i & 31;      // r = u_local, c = k4_local (coalesced read)
    tile[r][c] = w4[(size_t)(ut*32 + r)*2048 + kt*32 + c];
  }
  __syncthreads();
  for (int i = t; i < 1024; i += 256) {
    int r = i >> 5, c = i & 31;      // r = k4_local, c = u_local (coalesced write)
    wt4[(size_t)(kt*32 + r)*1024 + ut*32 + c] = tile[c][r];
  }
}

// ---------------- fc1 v3: tiled, order-preserving ----------------
// grid 256 = ug(128: 8 u each) x bg(2: 16 b each); block 128 = 8 u-lanes x 16 b
__global__ __launch_bounds__(128) void k_fc1v3(const float* __restrict__ p3,
    const float* __restrict__ wt, const float* __restrict__ bias,
    const float* __restrict__ mask, float* __restrict__ c1, float* __restrict__ sf1) {
  const float4* wt4 = (const float4*)wt;
  const float4* p34 = (const float4*)p3;
  int ug = blockIdx.x >> 1;
  int bg = blockIdx.x & 1;
  int u0 = ug * 8, b0 = bg * 16;
  int t = threadIdx.x;
  int u_l = t & 7, b_sub = t >> 3;

  __shared__ float4 sld[16 * 129];   // 16 b rows x 128 k4, pad->129 (33 KB)
  float acc = 0.f;

  for (int kc = 0; kc < 16; ++kc) {
    __syncthreads();
    for (int j = t; j < 16*128; j += 128) {
      int b_i = j >> 7, k4_i = j & 127;
      sld[b_i*129 + k4_i] = p34[(size_t)(b0 + b_i)*2048 + kc*128 + k4_i];
    }
    __syncthreads();
    const float4* wp = wt4 + (size_t)(kc*128)*1024 + u0 + u_l;
    const float4* sp = sld + b_sub*129;
    #pragma unroll 8
    for (int k4 = 0; k4 < 128; ++k4) {
      float4 wv = wp[(size_t)k4 * 1024];
      float4 sv = sp[k4];
      acc = fmaf(wv.x, sv.x, acc);
      acc = fmaf(wv.y, sv.y, acc);
      acc = fmaf(wv.z, sv.z, acc);
      acc = fmaf(wv.w, sv.w, acc);
    }
  }

  int u = u0 + u_l, b = b0 + b_sub;
  int mi = b * 1024 + u;
  float m = c1[mi] + acc + bias[u];
  float spk = (m >= 1.0f) ? 1.0f : 0.0f;
  c1[mi] = m - spk;
  sf1[mi] = spk * mask[mi];
}

// ---------------- fc1 fallback (ws too small for transpose) ----------------
__global__ __launch_bounds__(256) void k_fc1(const float* __restrict__ p3,
    const float* __restrict__ w, const float* __restrict__ bias,
    const float* __restrict__ mask, float* __restrict__ c1, float* __restrict__ sf1) {
  int t = threadIdx.x;
  int b  = t & 31;
  int ul = t >> 5;
  int u = blockIdx.x * 8 + ul;
  const float4* wp = (const float4*)(w + (size_t)u * 8192);
  const float4* sp = (const float4*)(p3 + (size_t)b * 8192);
  float acc = 0.f;
  #pragma unroll 8
  for (int i = 0; i < 2048; ++i) {
    float4 a = wp[i];
    float4 s = sp[i];
    acc = fmaf(a.x, s.x, acc);
    acc = fmaf(a.y, s.y, acc);
    acc = fmaf(a.z, s.z, acc);
    acc = fmaf(a.w, s.w, acc);
  }
  int mi = b * 1024 + u;
  float m = c1[mi] + acc + bias[u];
  float spk = (m >= 1.0f) ? 1.0f : 0.0f;
  c1[mi] = m - spk;
  sf1[mi] = spk * mask[mi];
}

// ---------------- fc2 (32x1024 @ 1024x10^T) + LIF(c2) -> out ----------------
__global__ __launch_bounds__(256) void k_fc2(const float* __restrict__ sf1,
    const float* __restrict__ w, const float* __restrict__ bias,
    float* __restrict__ c2, float* __restrict__ out) {
  int idx = blockIdx.x * 256 + threadIdx.x;
  if (idx >= 320) return;
  int u = idx >> 5;      // 0..9
  int b = idx & 31;
  const float4* wp = (const float4*)(w + u * 1024);
  const float4* sp = (const float4*)(sf1 + b * 1024);
  float acc = 0.f;
  #pragma unroll 4
  for (int i = 0; i < 256; ++i) {
    float4 a = wp[i];
    float4 s = sp[i];
    acc = fmaf(a.x, s.x, acc);
    acc = fmaf(a.y, s.y, acc);
    acc = fmaf(a.z, s.z, acc);
    acc = fmaf(a.w, s.w, acc);
  }
  int mi = b * 10 + u;
  float m = c2[mi] + acc + bias[u];
  float spk = (m >= 1.0f) ? 1.0f : 0.0f;
  m -= spk;
  c2[mi] = m;
  out[mi] = m;   // final timestep's write is the answer
}

extern "C" void kernel_launch(void* const* d_in, const int* in_sizes, int n_in,
                              void* d_out, int out_size, void* d_ws, size_t ws_size,
                              hipStream_t stream) {
  const float* X   = (const float*)d_in[0];
  const float* w1  = (const float*)d_in[1];
  const float* b1  = (const float*)d_in[2];
  const float* w2  = (const float*)d_in[3];
  const float* b2  = (const float*)d_in[4];
  const float* w3  = (const float*)d_in[5];
  const float* b3  = (const float*)d_in[6];
  const float* fw1 = (const float*)d_in[7];
  const float* fb1 = (const float*)d_in[8];
  const float* fw2 = (const float*)d_in[9];
  const float* fb2 = (const float*)d_in[10];
  const float* mf1 = (const float*)d_in[11];
  const float* mf2 = (const float*)d_in[12];
  const float* mc1 = (const float*)d_in[13];
  float* out = (float*)d_out;

  float* ws  = (float*)d_ws;
  float* A1  = ws + OFF_A1;
  float* m1  = ws + OFF_M1;
  float* s1  = ws + OFF_S1;
  float* m2  = ws + OFF_M2;
  float* p2  = ws + OFF_P2;
  float* m3  = ws + OFF_M3;
  float* p3  = ws + OFF_P3;
  float* c1  = ws + OFF_C1;
  float* sf1 = ws + OFF_SF1;
  float* c2  = ws + OFF_C2;
  float* wt  = ws + OFF_WT;

  const bool use_wt = ws_size >= ((size_t)OFF_WT + N_WT) * 4;  // constant per run

  // ws is poisoned 0xAA before every timed call: zero all LIF state.
  hipMemsetAsync(m1, 0, (size_t)N_L1 * 4, stream);                       // m1
  hipMemsetAsync(m2, 0, (size_t)(N_M2 + N_P2 + N_M3) * 4, stream);       // m2,p2,m3
  hipMemsetAsync(c1, 0, (size_t)(2*N_C1 + N_C2) * 4, stream);            // c1,sf1,c2

  // conv1 output is timestep-invariant: compute once.
  k_conv1<<<N_L1/256, 256, 0, stream>>>(X, w1, b1, A1);
  if (use_wt)
    k_wt<<<2048, 256, 0, stream>>>(fw1, wt);                             // once

  for (int t = 0; t < T_STEPS; ++t) {
    k_lif1<<<N_L1/256, 256, 0, stream>>>(A1, mf1, m1, s1);
    k_conv2<<<1024, 256, 0, stream>>>(s1, w2, b2, m2, p2);
    k_conv3<<<1024, 256, 0, stream>>>(p2, w3, b3, mf2, m3, p3);
    if (use_wt)
      k_fc1v3<<<256, 128, 0, stream>>>(p3, wt, fb1, mc1, c1, sf1);
    else
      k_fc1<<<128, 256, 0, stream>>>(p3, fw1, fb1, mc1, c1, sf1);
    k_fc2<<<2, 256, 0, stream>>>(sf1, fw2, fb2, c2, out);
  }
}

// Round 7
// 2933.984 us; speedup vs baseline: 1.9221x; 1.3204x over previous
//
#include <hip/hip_runtime.h>

#define T_STEPS 8

// ---- sizes (floats) ----
#define N_L1 (32*64*32*32)     // 2,097,152
#define N_M2 (32*128*32*32)    // 4,194,304
#define N_P2 (32*128*16*16)    // 1,048,576
#define N_M3 N_P2
#define N_P3 (32*8192)         // 262,144
#define N_C1 (32*1024)
#define N_C2 (32*10)

// ---- workspace offsets (floats) ----
#define OFF_A1  0
#define OFF_M1  (OFF_A1 + N_L1)
#define OFF_S1  (OFF_M1 + N_L1)
#define OFF_M2  (OFF_S1 + N_L1)
#define OFF_P2  (OFF_M2 + N_M2)
#define OFF_M3  (OFF_P2 + N_P2)
#define OFF_P3  (OFF_M3 + N_M3)
#define OFF_C1  (OFF_P3 + N_P3)
#define OFF_SF1 (OFF_C1 + N_C1)
#define OFF_C2  (OFF_SF1 + N_C1)

// ---------------- conv1 (runs once; X constant across timesteps) ----------------
__global__ __launch_bounds__(256) void k_conv1(const float* __restrict__ X,
    const float* __restrict__ w, const float* __restrict__ bias,
    float* __restrict__ A1) {
  int idx = blockIdx.x * 256 + threadIdx.x;          // (b,oc,y,x)
  int x = idx & 31, y = (idx >> 5) & 31, oc = (idx >> 10) & 63, b = idx >> 16;
  float acc = bias[oc];
  for (int ic = 0; ic < 3; ++ic) {
    const float* xp = X + (b*3 + ic)*1024;
    const float* wp = w + (oc*3 + ic)*9;
    #pragma unroll
    for (int dy = 0; dy < 3; ++dy) {
      int iy = y + dy - 1;
      if (iy < 0 || iy > 31) continue;
      #pragma unroll
      for (int dx = 0; dx < 3; ++dx) {
        int ix = x + dx - 1;
        if (ix < 0 || ix > 31) continue;
        acc = fmaf(xp[iy*32 + ix], wp[dy*3 + dx], acc);
      }
    }
  }
  A1[idx] = acc;
}

// ---------------- layer-1 LIF + dropout-mask (elementwise) ----------------
__global__ __launch_bounds__(256) void k_lif1(const float* __restrict__ A1,
    const float* __restrict__ mask, float* __restrict__ m1, float* __restrict__ s1) {
  int i = blockIdx.x * 256 + threadIdx.x;
  float m = m1[i] + A1[i];
  float spk = (m >= 1.0f) ? 1.0f : 0.0f;
  m1[i] = m - spk;
  s1[i] = spk * mask[i];
}

// ---------------- conv2 + LIF(m2) + 2x2 mean-pool (v3: 2x register tile) ----------------
// grid 1024: b(32) x yt(2: 16-row bands) x ocg(16: 8 oc each)
// block 256 = 16 xpair x 16 y; per thread: 2 x-outputs x 8 oc (16 acc)
__global__ __launch_bounds__(256, 4) void k_conv2(const float* __restrict__ s1,
    const float* __restrict__ w, const float* __restrict__ bias,
    float* __restrict__ m2, float* __restrict__ p2) {
  int bid = blockIdx.x;
  int ocg = bid & 15;
  int yt  = (bid >> 4) & 1;
  int b   = bid >> 5;
  int t = threadIdx.x;
  int xp = t & 15, ty = t >> 4;           // x = {2xp, 2xp+1}, row = ty (0..15)

  __shared__ float lds[8 * 612];          // 8 ic x 18 rows x 34 cols = 19.6 KB
  float acc[2][8];
  #pragma unroll
  for (int o = 0; o < 8; ++o) { acc[0][o] = 0.f; acc[1][o] = 0.f; }

  for (int chunk = 0; chunk < 8; ++chunk) {
    const float* src = s1 + (size_t)(b*64 + chunk*8) * 1024;
    __syncthreads();
    #pragma unroll
    for (int ic = 0; ic < 8; ++ic) {
      for (int j = t; j < 612; j += 256) {
        int ry = j / 34;
        int rx = j - ry*34;
        int iy = yt*16 + ry - 1;
        int ix = rx - 1;
        float v = 0.f;
        if ((unsigned)iy < 32u && (unsigned)ix < 32u)
          v = src[ic*1024 + iy*32 + ix];
        lds[ic*612 + j] = v;
      }
    }
    __syncthreads();
    const float* wc = w + ((size_t)(ocg*8)*64 + chunk*8)*9;
    for (int ic = 0; ic < 8; ++ic) {
      float in12[12];
      const float* lp = &lds[ic*612 + ty*34 + 2*xp];
      #pragma unroll
      for (int dy = 0; dy < 3; ++dy)
        #pragma unroll
        for (int dx = 0; dx < 4; ++dx)
          in12[dy*4+dx] = lp[dy*34 + dx];
      #pragma unroll
      for (int o = 0; o < 8; ++o) {
        const float* wp = wc + (o*64 + ic)*9;   // block-uniform -> s_load
        #pragma unroll
        for (int k = 0; k < 9; ++k) {
          const int dy = k/3, dx = k - 3*(k/3);  // compile-time
          acc[0][o] = fmaf(in12[dy*4+dx],   wp[k], acc[0][o]);
          acc[1][o] = fmaf(in12[dy*4+dx+1], wp[k], acc[1][o]);
        }
      }
    }
  }

  int y = yt*16 + ty;
  int x0 = 2*xp;
  bool ywriter = ((ty & 1) == 0);
  #pragma unroll
  for (int o = 0; o < 8; ++o) {
    int oc = ocg*8 + o;
    size_t mi = (size_t)(b*128 + oc)*1024 + y*32 + x0;
    float2 mv = *(const float2*)&m2[mi];
    float ma = mv.x + acc[0][o] + bias[oc];
    float mb = mv.y + acc[1][o] + bias[oc];
    float sa = (ma >= 1.0f) ? 1.0f : 0.0f;
    float sb = (mb >= 1.0f) ? 1.0f : 0.0f;
    float2 mo; mo.x = ma - sa; mo.y = mb - sb;
    *(float2*)&m2[mi] = mo;
    float s = sa + sb;
    s += __shfl_xor(s, 16);
    if (ywriter)
      p2[(size_t)(b*128 + oc)*256 + (y>>1)*16 + xp] = s * 0.25f;
  }
}

// ---------------- conv3 v2 + LIF(m3) + mask_f2 + 2x2 mean-pool ----------------
// grid 256: b(32) x og(8: 16 oc each); block 256 = oh(2: 8-oc half) x y(16) x xp(8)
// per thread: 2 x-outputs x 8 oc (16 acc); LDS chunk 8 ic x 18 x 20, double-buffered
// weights via readfirstlane(ocb) -> SGPR s_loads; row stride 20 -> bank offsets
// {0,20,8,28,16,4,24,12} distinct mod 32
__global__ __launch_bounds__(256, 2) void k_conv3(const float* __restrict__ p2,
    const float* __restrict__ w, const float* __restrict__ bias,
    const float* __restrict__ mf2, float* __restrict__ m3, float* __restrict__ p3) {
  int og = blockIdx.x & 7;
  int b  = blockIdx.x >> 3;
  int t = threadIdx.x;
  int xp = t & 7, y = (t >> 3) & 15, oh = t >> 7;
  // wave-uniform (lanes 0..63 share t>>7) -> SGPR so weight reads stay s_loads
  int ocb = __builtin_amdgcn_readfirstlane(og*16 + oh*8);

  __shared__ float lds[2][8 * 360];       // dbuf x (8 ic x 18 x 20) = 22.5 KB
  float acc[2][8];
  #pragma unroll
  for (int o = 0; o < 8; ++o) { acc[0][o] = 0.f; acc[1][o] = 0.f; }

  #define STAGE3(chunk, dst) {                                          \
    const float* src = p2 + (size_t)(b*128 + (chunk)*8) * 256;          \
    for (int j = t; j < 2880; j += 256) {                               \
      int ic = j / 360;                                                 \
      int r  = j - ic*360;                                              \
      int ry = r / 20;                                                  \
      int rx = r - ry*20;                                               \
      if (rx < 18) {                                                    \
        int iy = ry - 1, ix = rx - 1;                                   \
        float v = 0.f;                                                  \
        if ((unsigned)iy < 16u && (unsigned)ix < 16u)                   \
          v = src[ic*256 + iy*16 + ix];                                 \
        (dst)[j] = v;                                                   \
      }                                                                 \
    }                                                                   \
  }

  STAGE3(0, lds[0]);
  __syncthreads();
  int buf = 0;
  for (int chunk = 0; chunk < 16; ++chunk) {
    if (chunk + 1 < 16) STAGE3(chunk + 1, lds[buf ^ 1]);   // prefetch next
    const float* wc = w + ((size_t)ocb*128 + chunk*8)*9;
    for (int ic = 0; ic < 8; ++ic) {
      float in12[12];
      const float* lp = &lds[buf][ic*360 + y*20 + 2*xp];
      #pragma unroll
      for (int dy = 0; dy < 3; ++dy)
        #pragma unroll
        for (int dx = 0; dx < 4; ++dx)
          in12[dy*4+dx] = lp[dy*20 + dx];
      #pragma unroll
      for (int o = 0; o < 8; ++o) {
        const float* wp = wc + (o*128 + ic)*9;
        #pragma unroll
        for (int k = 0; k < 9; ++k) {
          const int dy = k/3, dx = k - 3*(k/3);
          acc[0][o] = fmaf(in12[dy*4+dx],   wp[k], acc[0][o]);
          acc[1][o] = fmaf(in12[dy*4+dx+1], wp[k], acc[1][o]);
        }
      }
    }
    __syncthreads();
    buf ^= 1;
  }

  // epilogue: bias + LIF + mask-before-pool; x-pair in-thread (s_even + s_odd,
  // same order as old shfl_xor(1)), y-pair via shfl_xor(8) (lane bit3 = y bit0)
  int x0 = 2*xp;
  bool ywriter = ((y & 1) == 0);
  #pragma unroll
  for (int o = 0; o < 8; ++o) {
    int oc = ocb + o;
    size_t base = (size_t)(b*128 + oc)*256 + y*16 + x0;
    float2 mv = *(const float2*)&m3[base];
    float2 fv = *(const float2*)&mf2[base];
    float ma = mv.x + acc[0][o] + bias[oc];
    float mb = mv.y + acc[1][o] + bias[oc];
    float sa = (ma >= 1.0f) ? 1.0f : 0.0f;
    float sb = (mb >= 1.0f) ? 1.0f : 0.0f;
    float2 mo; mo.x = ma - sa; mo.y = mb - sb;
    *(float2*)&m3[base] = mo;
    float s = sa * fv.x + sb * fv.y;
    s += __shfl_xor(s, 8);
    if (ywriter)
      p3[(size_t)b*8192 + oc*64 + (y>>1)*8 + xp] = s * 0.25f;
  }
}

// ---------------- fc1 v4: LDS-staged, order-preserving serial chain ----------------
// grid 256 = ug(128: 8 u) x bg(2: 16 b); block 128 = 8 u-lanes x 16 b
// Per chunk KC=512: stage w (8 rows, k-contiguous from original fw1 -> coalesced)
// and s into LDS; each thread runs 512 in-order FMAs (float4 x,y,z,w = ascending k).
// Banks: s stride 129 f4 (516 fl = 4 mod 32) -> 8 b-rows cover 32 banks exactly;
// w stride 130 f4 (520 fl = 8 mod 32) -> 2-way (free), lane replicas broadcast.
__global__ __launch_bounds__(128) void k_fc1v4(const float* __restrict__ p3,
    const float* __restrict__ w, const float* __restrict__ bias,
    const float* __restrict__ mask, float* __restrict__ c1, float* __restrict__ sf1) {
  const float4* w4  = (const float4*)w;
  const float4* p34 = (const float4*)p3;
  int ug = blockIdx.x >> 1;
  int bg = blockIdx.x & 1;
  int u0 = ug * 8, b0 = bg * 16;
  int t = threadIdx.x;
  int u_l = t & 7, b_sub = t >> 3;       // u fastest -> coalesced c1/sf1 epilogue

  __shared__ float4 lds4[8*130 + 16*129];  // w | s = 49.7 KB
  float4* wl = lds4;
  float4* sl = lds4 + 8*130;

  float acc = 0.f;
  for (int kc = 0; kc < 16; ++kc) {
    __syncthreads();
    #pragma unroll
    for (int j0 = 0; j0 < 1024; j0 += 128) {
      int j = j0 + t;
      int u_i = j >> 7, k4 = j & 127;
      wl[u_i*130 + k4] = w4[(size_t)(u0 + u_i)*2048 + kc*128 + k4];
    }
    #pragma unroll
    for (int j0 = 0; j0 < 2048; j0 += 128) {
      int j = j0 + t;
      int b_i = j >> 7, k4 = j & 127;
      sl[b_i*129 + k4] = p34[(size_t)(b0 + b_i)*2048 + kc*128 + k4];
    }
    __syncthreads();
    const float4* wp = wl + u_l*130;
    const float4* sp = sl + b_sub*129;
    #pragma unroll 8
    for (int k4 = 0; k4 < 128; ++k4) {
      float4 wv = wp[k4];
      float4 sv = sp[k4];
      acc = fmaf(wv.x, sv.x, acc);
      acc = fmaf(wv.y, sv.y, acc);
      acc = fmaf(wv.z, sv.z, acc);
      acc = fmaf(wv.w, sv.w, acc);
    }
  }

  int u = u0 + u_l, b = b0 + b_sub;
  int mi = b * 1024 + u;
  float m = c1[mi] + acc + bias[u];
  float spk = (m >= 1.0f) ? 1.0f : 0.0f;
  c1[mi] = m - spk;
  sf1[mi] = spk * mask[mi];
}

// ---------------- fc2 (32x1024 @ 1024x10^T) + LIF(c2) -> out ----------------
__global__ __launch_bounds__(256) void k_fc2(const float* __restrict__ sf1,
    const float* __restrict__ w, const float* __restrict__ bias,
    float* __restrict__ c2, float* __restrict__ out) {
  int idx = blockIdx.x * 256 + threadIdx.x;
  if (idx >= 320) return;
  int u = idx >> 5;      // 0..9
  int b = idx & 31;
  const float4* wp = (const float4*)(w + u * 1024);
  const float4* sp = (const float4*)(sf1 + b * 1024);
  float acc = 0.f;
  #pragma unroll 4
  for (int i = 0; i < 256; ++i) {
    float4 a = wp[i];
    float4 s = sp[i];
    acc = fmaf(a.x, s.x, acc);
    acc = fmaf(a.y, s.y, acc);
    acc = fmaf(a.z, s.z, acc);
    acc = fmaf(a.w, s.w, acc);
  }
  int mi = b * 10 + u;
  float m = c2[mi] + acc + bias[u];
  float spk = (m >= 1.0f) ? 1.0f : 0.0f;
  m -= spk;
  c2[mi] = m;
  out[mi] = m;   // final timestep's write is the answer
}

extern "C" void kernel_launch(void* const* d_in, const int* in_sizes, int n_in,
                              void* d_out, int out_size, void* d_ws, size_t ws_size,
                              hipStream_t stream) {
  const float* X   = (const float*)d_in[0];
  const float* w1  = (const float*)d_in[1];
  const float* b1  = (const float*)d_in[2];
  const float* w2  = (const float*)d_in[3];
  const float* b2  = (const float*)d_in[4];
  const float* w3  = (const float*)d_in[5];
  const float* b3  = (const float*)d_in[6];
  const float* fw1 = (const float*)d_in[7];
  const float* fb1 = (const float*)d_in[8];
  const float* fw2 = (const float*)d_in[9];
  const float* fb2 = (const float*)d_in[10];
  const float* mf1 = (const float*)d_in[11];
  const float* mf2 = (const float*)d_in[12];
  const float* mc1 = (const float*)d_in[13];
  float* out = (float*)d_out;

  float* ws  = (float*)d_ws;
  float* A1  = ws + OFF_A1;
  float* m1  = ws + OFF_M1;
  float* s1  = ws + OFF_S1;
  float* m2  = ws + OFF_M2;
  float* p2  = ws + OFF_P2;
  float* m3  = ws + OFF_M3;
  float* p3  = ws + OFF_P3;
  float* c1  = ws + OFF_C1;
  float* sf1 = ws + OFF_SF1;
  float* c2  = ws + OFF_C2;

  // ws is poisoned 0xAA before every timed call: zero all LIF state.
  hipMemsetAsync(m1, 0, (size_t)N_L1 * 4, stream);                       // m1
  hipMemsetAsync(m2, 0, (size_t)(N_M2 + N_P2 + N_M3) * 4, stream);       // m2,p2,m3
  hipMemsetAsync(c1, 0, (size_t)(2*N_C1 + N_C2) * 4, stream);            // c1,sf1,c2

  // conv1 output is timestep-invariant: compute once.
  k_conv1<<<N_L1/256, 256, 0, stream>>>(X, w1, b1, A1);

  for (int t = 0; t < T_STEPS; ++t) {
    k_lif1<<<N_L1/256, 256, 0, stream>>>(A1, mf1, m1, s1);
    k_conv2<<<1024, 256, 0, stream>>>(s1, w2, b2, m2, p2);
    k_conv3<<<256, 256, 0, stream>>>(p2, w3, b3, mf2, m3, p3);
    k_fc1v4<<<256, 128, 0, stream>>>(p3, fw1, fb1, mc1, c1, sf1);
    k_fc2<<<2, 256, 0, stream>>>(sf1, fw2, fb2, c2, out);
  }
}

// Round 8
// 2849.260 us; speedup vs baseline: 1.9792x; 1.0297x over previous
//
#include <hip/hip_runtime.h>

#define T_STEPS 8

// ---- sizes (floats) ----
#define N_L1 (32*64*32*32)     // 2,097,152
#define N_M2 (32*128*32*32)    // 4,194,304
#define N_P2 (32*128*16*16)    // 1,048,576
#define N_M3 N_P2
#define N_P3 (32*8192)         // 262,144
#define N_C1 (32*1024)
#define N_C2 (32*10)

// ---- workspace offsets (floats) ----
#define OFF_A1  0
#define OFF_M1  (OFF_A1 + N_L1)
#define OFF_S1  (OFF_M1 + N_L1)
#define OFF_M2  (OFF_S1 + N_L1)
#define OFF_P2  (OFF_M2 + N_M2)
#define OFF_M3  (OFF_P2 + N_P2)
#define OFF_P3  (OFF_M3 + N_M3)
#define OFF_C1  (OFF_P3 + N_P3)
#define OFF_SF1 (OFF_C1 + N_C1)
#define OFF_C2  (OFF_SF1 + N_C1)

// ---------------- conv1 (runs once; X constant across timesteps) ----------------
__global__ __launch_bounds__(256) void k_conv1(const float* __restrict__ X,
    const float* __restrict__ w, const float* __restrict__ bias,
    float* __restrict__ A1) {
  int idx = blockIdx.x * 256 + threadIdx.x;          // (b,oc,y,x)
  int x = idx & 31, y = (idx >> 5) & 31, oc = (idx >> 10) & 63, b = idx >> 16;
  float acc = bias[oc];
  for (int ic = 0; ic < 3; ++ic) {
    const float* xp = X + (b*3 + ic)*1024;
    const float* wp = w + (oc*3 + ic)*9;
    #pragma unroll
    for (int dy = 0; dy < 3; ++dy) {
      int iy = y + dy - 1;
      if (iy < 0 || iy > 31) continue;
      #pragma unroll
      for (int dx = 0; dx < 3; ++dx) {
        int ix = x + dx - 1;
        if (ix < 0 || ix > 31) continue;
        acc = fmaf(xp[iy*32 + ix], wp[dy*3 + dx], acc);
      }
    }
  }
  A1[idx] = acc;
}

// ---------------- layer-1 LIF + dropout-mask (float4 elementwise) ----------------
__global__ __launch_bounds__(256) void k_lif1(const float4* __restrict__ A1,
    const float4* __restrict__ mask, float4* __restrict__ m1, float4* __restrict__ s1) {
  int i = blockIdx.x * 256 + threadIdx.x;            // N_L1/4 elements
  float4 m = m1[i], a = A1[i], k = mask[i], s;
  m.x += a.x; { float p = (m.x >= 1.0f) ? 1.0f : 0.0f; m.x -= p; s.x = p * k.x; }
  m.y += a.y; { float p = (m.y >= 1.0f) ? 1.0f : 0.0f; m.y -= p; s.y = p * k.y; }
  m.z += a.z; { float p = (m.z >= 1.0f) ? 1.0f : 0.0f; m.z -= p; s.z = p * k.z; }
  m.w += a.w; { float p = (m.w >= 1.0f) ? 1.0f : 0.0f; m.w -= p; s.w = p * k.w; }
  m1[i] = m;
  s1[i] = s;
}

// ---------------- conv2 + LIF(m2) + 2x2 mean-pool (v3: 2x register tile) ----------------
// grid 1024: b(32) x yt(2: 16-row bands) x ocg(16: 8 oc each)
// block 256 = 16 xpair x 16 y; per thread: 2 x-outputs x 8 oc (16 acc)
__global__ __launch_bounds__(256, 4) void k_conv2(const float* __restrict__ s1,
    const float* __restrict__ w, const float* __restrict__ bias,
    float* __restrict__ m2, float* __restrict__ p2) {
  int bid = blockIdx.x;
  int ocg = bid & 15;
  int yt  = (bid >> 4) & 1;
  int b   = bid >> 5;
  int t = threadIdx.x;
  int xp = t & 15, ty = t >> 4;           // x = {2xp, 2xp+1}, row = ty (0..15)

  __shared__ float lds[8 * 612];          // 8 ic x 18 rows x 34 cols = 19.6 KB
  float acc[2][8];
  #pragma unroll
  for (int o = 0; o < 8; ++o) { acc[0][o] = 0.f; acc[1][o] = 0.f; }

  for (int chunk = 0; chunk < 8; ++chunk) {
    const float* src = s1 + (size_t)(b*64 + chunk*8) * 1024;
    __syncthreads();
    #pragma unroll
    for (int ic = 0; ic < 8; ++ic) {
      for (int j = t; j < 612; j += 256) {
        int ry = j / 34;
        int rx = j - ry*34;
        int iy = yt*16 + ry - 1;
        int ix = rx - 1;
        float v = 0.f;
        if ((unsigned)iy < 32u && (unsigned)ix < 32u)
          v = src[ic*1024 + iy*32 + ix];
        lds[ic*612 + j] = v;
      }
    }
    __syncthreads();
    const float* wc = w + ((size_t)(ocg*8)*64 + chunk*8)*9;
    for (int ic = 0; ic < 8; ++ic) {
      float in12[12];
      const float* lp = &lds[ic*612 + ty*34 + 2*xp];
      #pragma unroll
      for (int dy = 0; dy < 3; ++dy)
        #pragma unroll
        for (int dx = 0; dx < 4; ++dx)
          in12[dy*4+dx] = lp[dy*34 + dx];
      #pragma unroll
      for (int o = 0; o < 8; ++o) {
        const float* wp = wc + (o*64 + ic)*9;   // block-uniform -> s_load
        #pragma unroll
        for (int k = 0; k < 9; ++k) {
          const int dy = k/3, dx = k - 3*(k/3);  // compile-time
          acc[0][o] = fmaf(in12[dy*4+dx],   wp[k], acc[0][o]);
          acc[1][o] = fmaf(in12[dy*4+dx+1], wp[k], acc[1][o]);
        }
      }
    }
  }

  int y = yt*16 + ty;
  int x0 = 2*xp;
  bool ywriter = ((ty & 1) == 0);
  #pragma unroll
  for (int o = 0; o < 8; ++o) {
    int oc = ocg*8 + o;
    size_t mi = (size_t)(b*128 + oc)*1024 + y*32 + x0;
    float2 mv = *(const float2*)&m2[mi];
    float ma = mv.x + acc[0][o] + bias[oc];
    float mb = mv.y + acc[1][o] + bias[oc];
    float sa = (ma >= 1.0f) ? 1.0f : 0.0f;
    float sb = (mb >= 1.0f) ? 1.0f : 0.0f;
    float2 mo; mo.x = ma - sa; mo.y = mb - sb;
    *(float2*)&m2[mi] = mo;
    float s = sa + sb;
    s += __shfl_xor(s, 16);
    if (ywriter)
      p2[(size_t)(b*128 + oc)*256 + (y>>1)*16 + xp] = s * 0.25f;
  }
}

// ---------------- conv3 v3 + LIF(m3) + mask_f2 + 2x2 mean-pool ----------------
// conv2-regime copy: grid 1024 = b(32) x ocg(32: 4 oc each); block 256 = 16x x 16y
// thread: 1 x-output x 4 oc; LDS chunk 8 ic x 18 x 20 (stride 20, single-float
// reads: ty bank offs {0,20,8,28} + tx 0..15 -> exact 2 lanes/bank = free)
__global__ __launch_bounds__(256, 4) void k_conv3(const float* __restrict__ p2,
    const float* __restrict__ w, const float* __restrict__ bias,
    const float* __restrict__ mf2, float* __restrict__ m3, float* __restrict__ p3) {
  int ocg = blockIdx.x & 31;
  int b   = blockIdx.x >> 5;
  int t = threadIdx.x;
  int tx = t & 15, ty = t >> 4;

  __shared__ float lds[8 * 360];          // 8 ic x 18 rows x 20 cols = 11.5 KB
  float acc[4];
  #pragma unroll
  for (int o = 0; o < 4; ++o) acc[o] = 0.f;

  for (int chunk = 0; chunk < 16; ++chunk) {
    const float* src = p2 + (size_t)(b*128 + chunk*8) * 256;
    __syncthreads();
    for (int j = t; j < 2880; j += 256) {
      int ic = j / 360;
      int r  = j - ic*360;
      int ry = r / 20;
      int rx = r - ry*20;
      if (rx < 18) {
        int iy = ry - 1, ix = rx - 1;
        float v = 0.f;
        if ((unsigned)iy < 16u && (unsigned)ix < 16u)
          v = src[ic*256 + iy*16 + ix];
        lds[j] = v;
      }
    }
    __syncthreads();
    const float* wc = w + ((size_t)(ocg*4)*128 + chunk*8)*9;
    for (int ic = 0; ic < 8; ++ic) {
      float in9[9];
      const float* lp = &lds[ic*360 + ty*20 + tx];
      #pragma unroll
      for (int dy = 0; dy < 3; ++dy)
        #pragma unroll
        for (int dx = 0; dx < 3; ++dx)
          in9[dy*3+dx] = lp[dy*20 + dx];
      #pragma unroll
      for (int o = 0; o < 4; ++o) {
        const float* wp = wc + (o*128 + ic)*9;  // block-uniform -> s_load (18.4 KB set)
        #pragma unroll
        for (int k = 0; k < 9; ++k)
          acc[o] = fmaf(in9[k], wp[k], acc[o]);
      }
    }
  }

  // epilogue identical to v1 (verified bit-exact): mask before pool,
  // x-pair via shfl_xor(1), y-pair via shfl_xor(16)
  bool writer = ((tx & 1) == 0) && ((ty & 1) == 0);
  #pragma unroll
  for (int o = 0; o < 4; ++o) {
    int oc = ocg*4 + o;
    size_t base = (size_t)(b*128 + oc)*256 + ty*16 + tx;
    float m = m3[base] + acc[o] + bias[oc];
    float spk = (m >= 1.0f) ? 1.0f : 0.0f;
    m3[base] = m - spk;
    float s = spk * mf2[base];
    s += __shfl_xor(s, 1);
    s += __shfl_xor(s, 16);
    if (writer)
      p3[(size_t)b*8192 + oc*64 + (ty>>1)*8 + (tx>>1)] = s * 0.25f;
  }
}

// ---------------- fc1 v4: LDS-staged, order-preserving serial chain ----------------
// grid 256 = ug(128: 8 u) x bg(2: 16 b); block 128 = 8 u-lanes x 16 b
__global__ __launch_bounds__(128) void k_fc1v4(const float* __restrict__ p3,
    const float* __restrict__ w, const float* __restrict__ bias,
    const float* __restrict__ mask, float* __restrict__ c1, float* __restrict__ sf1) {
  const float4* w4  = (const float4*)w;
  const float4* p34 = (const float4*)p3;
  int ug = blockIdx.x >> 1;
  int bg = blockIdx.x & 1;
  int u0 = ug * 8, b0 = bg * 16;
  int t = threadIdx.x;
  int u_l = t & 7, b_sub = t >> 3;       // u fastest -> coalesced c1/sf1 epilogue

  __shared__ float4 lds4[8*130 + 16*129];  // w | s = 49.7 KB
  float4* wl = lds4;
  float4* sl = lds4 + 8*130;

  float acc = 0.f;
  for (int kc = 0; kc < 16; ++kc) {
    __syncthreads();
    #pragma unroll
    for (int j0 = 0; j0 < 1024; j0 += 128) {
      int j = j0 + t;
      int u_i = j >> 7, k4 = j & 127;
      wl[u_i*130 + k4] = w4[(size_t)(u0 + u_i)*2048 + kc*128 + k4];
    }
    #pragma unroll
    for (int j0 = 0; j0 < 2048; j0 += 128) {
      int j = j0 + t;
      int b_i = j >> 7, k4 = j & 127;
      sl[b_i*129 + k4] = p34[(size_t)(b0 + b_i)*2048 + kc*128 + k4];
    }
    __syncthreads();
    const float4* wp = wl + u_l*130;
    const float4* sp = sl + b_sub*129;
    #pragma unroll 8
    for (int k4 = 0; k4 < 128; ++k4) {
      float4 wv = wp[k4];
      float4 sv = sp[k4];
      acc = fmaf(wv.x, sv.x, acc);
      acc = fmaf(wv.y, sv.y, acc);
      acc = fmaf(wv.z, sv.z, acc);
      acc = fmaf(wv.w, sv.w, acc);
    }
  }

  int u = u0 + u_l, b = b0 + b_sub;
  int mi = b * 1024 + u;
  float m = c1[mi] + acc + bias[u];
  float spk = (m >= 1.0f) ? 1.0f : 0.0f;
  c1[mi] = m - spk;
  sf1[mi] = spk * mask[mi];
}

// ---------------- fc2 (32x1024 @ 1024x10^T) + LIF(c2) -> out ----------------
__global__ __launch_bounds__(256) void k_fc2(const float* __restrict__ sf1,
    const float* __restrict__ w, const float* __restrict__ bias,
    float* __restrict__ c2, float* __restrict__ out) {
  int idx = blockIdx.x * 256 + threadIdx.x;
  if (idx >= 320) return;
  int u = idx >> 5;      // 0..9
  int b = idx & 31;
  const float4* wp = (const float4*)(w + u * 1024);
  const float4* sp = (const float4*)(sf1 + b * 1024);
  float acc = 0.f;
  #pragma unroll 4
  for (int i = 0; i < 256; ++i) {
    float4 a = wp[i];
    float4 s = sp[i];
    acc = fmaf(a.x, s.x, acc);
    acc = fmaf(a.y, s.y, acc);
    acc = fmaf(a.z, s.z, acc);
    acc = fmaf(a.w, s.w, acc);
  }
  int mi = b * 10 + u;
  float m = c2[mi] + acc + bias[u];
  float spk = (m >= 1.0f) ? 1.0f : 0.0f;
  m -= spk;
  c2[mi] = m;
  out[mi] = m;   // final timestep's write is the answer
}

extern "C" void kernel_launch(void* const* d_in, const int* in_sizes, int n_in,
                              void* d_out, int out_size, void* d_ws, size_t ws_size,
                              hipStream_t stream) {
  const float* X   = (const float*)d_in[0];
  const float* w1  = (const float*)d_in[1];
  const float* b1  = (const float*)d_in[2];
  const float* w2  = (const float*)d_in[3];
  const float* b2  = (const float*)d_in[4];
  const float* w3  = (const float*)d_in[5];
  const float* b3  = (const float*)d_in[6];
  const float* fw1 = (const float*)d_in[7];
  const float* fb1 = (const float*)d_in[8];
  const float* fw2 = (const float*)d_in[9];
  const float* fb2 = (const float*)d_in[10];
  const float* mf1 = (const float*)d_in[11];
  const float* mf2 = (const float*)d_in[12];
  const float* mc1 = (const float*)d_in[13];
  float* out = (float*)d_out;

  float* ws  = (float*)d_ws;
  float* A1  = ws + OFF_A1;
  float* m1  = ws + OFF_M1;
  float* s1  = ws + OFF_S1;
  float* m2  = ws + OFF_M2;
  float* p2  = ws + OFF_P2;
  float* m3  = ws + OFF_M3;
  float* p3  = ws + OFF_P3;
  float* c1  = ws + OFF_C1;
  float* sf1 = ws + OFF_SF1;
  float* c2  = ws + OFF_C2;

  // ws is poisoned 0xAA before every timed call: zero all LIF state.
  hipMemsetAsync(m1, 0, (size_t)N_L1 * 4, stream);                       // m1
  hipMemsetAsync(m2, 0, (size_t)(N_M2 + N_P2 + N_M3) * 4, stream);       // m2,p2,m3
  hipMemsetAsync(c1, 0, (size_t)(2*N_C1 + N_C2) * 4, stream);            // c1,sf1,c2

  // conv1 output is timestep-invariant: compute once.
  k_conv1<<<N_L1/256, 256, 0, stream>>>(X, w1, b1, A1);

  for (int t = 0; t < T_STEPS; ++t) {
    k_lif1<<<N_L1/4/256, 256, 0, stream>>>((const float4*)A1, (const float4*)mf1,
                                           (float4*)m1, (float4*)s1);
    k_conv2<<<1024, 256, 0, stream>>>(s1, w2, b2, m2, p2);
    k_conv3<<<1024, 256, 0, stream>>>(p2, w3, b3, mf2, m3, p3);
    k_fc1v4<<<256, 128, 0, stream>>>(p3, fw1, fb1, mc1, c1, sf1);
    k_fc2<<<2, 256, 0, stream>>>(sf1, fw2, fb2, c2, out);
  }
}